// Round 10
// baseline (365.263 us; speedup 1.0000x reference)
//
#include <hip/hip_runtime.h>
#include <math.h>

#define H 4096
#define NE 64
#define KTOP 8
#define TTOT 16384
#define BT1 32
#define NB1 (TTOT / BT1)        // 512 pass1 blocks
#define BT2 64
#define NB2 (TTOT / BT2)        // 256 pass2 blocks
#define TAU 1e-4f
#define DELTA 1e-3f

typedef __attribute__((ext_vector_type(8))) short bf16x8;
typedef __attribute__((ext_vector_type(4))) float f32x4;

union U4S8 { uint4 u; bf16x8 s; };

__device__ __forceinline__ unsigned bf16_rne(float f) {
  unsigned b = __float_as_uint(f);
  b += 0x7fffu + ((b >> 16) & 1u);
  return b >> 16;
}

// w fp32 -> hi/lo bf16, pre-swizzled per-32k-chunk images (round-5 proven).
// Chunk c image: 256 uint4; index = e*4 + (s ^ ((e>>1)&3)), holding
// w[e][c*32 + s*8 .. +7]. hi = images 0..127, lo = +128*256 uint4.
__global__ __launch_bounds__(256) void w_prep(const float* __restrict__ w,
                                              uint4* __restrict__ wsimg) {
  const int sid = blockIdx.x * 256 + threadIdx.x;   // 0..32767
  const int e = sid >> 9;
  const int rem = sid & 511;
  const int c = rem >> 2;
  const int s = rem & 3;
  const float* src = w + (size_t)e * H + c * 32 + s * 8;
  float4 f0 = *(const float4*)src;
  float4 f1 = *(const float4*)(src + 4);
  float xf[8] = {f0.x, f0.y, f0.z, f0.w, f1.x, f1.y, f1.z, f1.w};
  unsigned hu[8], lu[8];
#pragma unroll
  for (int j = 0; j < 8; ++j) {
    hu[j] = bf16_rne(xf[j]);
    float hf = __uint_as_float(hu[j] << 16);
    lu[j] = bf16_rne(xf[j] - hf);
  }
  uint4 hp, lp;
  hp.x = hu[0] | (hu[1] << 16); hp.y = hu[2] | (hu[3] << 16);
  hp.z = hu[4] | (hu[5] << 16); hp.w = hu[6] | (hu[7] << 16);
  lp.x = lu[0] | (lu[1] << 16); lp.y = lu[2] | (lu[3] << 16);
  lp.z = lu[4] | (lu[5] << 16); lp.w = lu[6] | (lu[7] << 16);
  const int slotp = s ^ ((e >> 1) & 3);
  wsimg[(size_t)c * 256 + e * 4 + slotp] = hp;
  wsimg[(size_t)128 * 256 + (size_t)c * 256 + e * 4 + slotp] = lp;
}

// fp32x8 -> bf16 hi frag + residual lo frag (packed RNE cvt).
__device__ __forceinline__ void cvt_split(const float4 a, const float4 b,
                                          bf16x8* hi, bf16x8* lo) {
  float xf[8] = {a.x, a.y, a.z, a.w, b.x, b.y, b.z, b.w};
  unsigned ph[4], pl[4];
#pragma unroll
  for (int q = 0; q < 4; ++q)
    asm("v_cvt_pk_bf16_f32 %0, %1, %2" : "=v"(ph[q])
        : "v"(xf[2 * q]), "v"(xf[2 * q + 1]));
  float rs[8];
#pragma unroll
  for (int q = 0; q < 4; ++q) {
    rs[2 * q]     = xf[2 * q]     - __uint_as_float(ph[q] << 16);
    rs[2 * q + 1] = xf[2 * q + 1] - __uint_as_float(ph[q] & 0xffff0000u);
  }
#pragma unroll
  for (int q = 0; q < 4; ++q)
    asm("v_cvt_pk_bf16_f32 %0, %1, %2" : "=v"(pl[q])
        : "v"(rs[2 * q]), "v"(rs[2 * q + 1]));
  U4S8 h, l;
  h.u = (uint4){ph[0], ph[1], ph[2], ph[3]};
  l.u = (uint4){pl[0], pl[1], pl[2], pl[3]};
  *hi = h.s;
  *lo = l.s;
}

#define GLDS(GP, LP)                                                   \
  __builtin_amdgcn_global_load_lds(                                    \
      (const __attribute__((address_space(1))) void*)(GP),             \
      (__attribute__((address_space(3))) void*)(LP), 16, 0, 0)

// Pass 1: bf16-split MFMA router GEMM. Single-wave blocks (NO barriers),
// grid 512, 2 independent blocks/CU. Wave = 32 tokens (2 A-tiles) x 64
// experts x full K. Depth-4 LDS ring, K-step 32, counted vmcnt only.
// Buffer (12 KB): [0,2K) x tile0 (swizzled), [2K,4K) x tile1,
// [4K,8K) w hi image, [8K,12K) w lo image.
__global__ __launch_bounds__(64, 1) void moe_pass1(
    const float* __restrict__ x, const uint4* __restrict__ wsimg,
    float* __restrict__ out, unsigned* __restrict__ wmask,
    float* __restrict__ waux) {
  extern __shared__ __align__(16) char smraw[];
  const int lane = threadIdx.x;        // 64 threads = 1 wave
  const int tok0 = blockIdx.x * BT1;
  const int trow = lane & 15;
  const int kgrp = lane >> 4;

  // x staging sources: issue (t,j) covers tile-t LDS bytes [j*1024+lane*16).
  // row = j*8 + (lane>>3), inrow = (lane&7)*16; source pre-XOR-swizzled.
  const char* xsrc[2][2];
#pragma unroll
  for (int t = 0; t < 2; ++t)
#pragma unroll
    for (int j = 0; j < 2; ++j) {
      const int row = j * 8 + (lane >> 3);
      const int inrow = (lane & 7) * 16;
      const int sin = inrow ^ ((row & 7) << 4);
      xsrc[t][j] = (const char*)(x + (size_t)(tok0 + t * 16 + row) * H) + sin;
    }
  const uint4* wsrcb[2] = {wsimg, wsimg + 128 * 256};

  f32x4 acc[2][4];
#pragma unroll
  for (int t = 0; t < 2; ++t)
#pragma unroll
    for (int et = 0; et < 4; ++et) acc[t][et] = (f32x4){0.f, 0.f, 0.f, 0.f};

#define ISSUE_STEP(KC, BUF)                                              \
  do {                                                                   \
    char* bb = smraw + (size_t)(BUF) * 12288;                            \
    _Pragma("unroll") for (int t = 0; t < 2; ++t)                        \
      _Pragma("unroll") for (int j = 0; j < 2; ++j)                      \
        GLDS(xsrc[t][j] + (size_t)(KC) * 128, bb + t * 2048 + j * 1024); \
    _Pragma("unroll") for (int j = 0; j < 8; ++j)                        \
      GLDS((const char*)(wsrcb[j >> 2] + (size_t)(KC) * 256 +            \
                         (j & 3) * 64 + lane),                           \
           bb + 4096 + (j >> 2) * 4096 + (j & 3) * 1024);                \
  } while (0)

  // prologue: 3 steps in flight (36 loads)
  ISSUE_STEP(0, 0);
  ISSUE_STEP(1, 1);
  ISSUE_STEP(2, 2);

  const int sx = (trow & 7) << 4;
  int entry[4];
#pragma unroll
  for (int et = 0; et < 4; ++et) {
    const int e = et * 16 + trow;
    entry[et] = (e * 4 + (kgrp ^ ((e >> 1) & 3))) * 16;
  }

  // main loop: 128 K-steps of 32 k, no barrier, counted vmcnt
#pragma unroll 1
  for (int kc = 0; kc < 128; ++kc) {
    if (kc < 126) {
      asm volatile("s_waitcnt vmcnt(24)" ::: "memory");
    } else if (kc == 126) {
      asm volatile("s_waitcnt vmcnt(12)" ::: "memory");
    } else {
      asm volatile("s_waitcnt vmcnt(0)" ::: "memory");
    }
    if (kc + 3 < 128) ISSUE_STEP(kc + 3, (kc + 3) & 3);

    const char* bufp = smraw + (size_t)(kc & 3) * 12288;
    bf16x8 ah[2], al[2];
#pragma unroll
    for (int t = 0; t < 2; ++t) {
      const char* ab = bufp + t * 2048 + trow * 128;
      float4 v0 = *(const float4*)(ab + ((kgrp * 32) ^ sx));
      float4 v1 = *(const float4*)(ab + ((kgrp * 32 + 16) ^ sx));
      cvt_split(v0, v1, &ah[t], &al[t]);
    }
#pragma unroll
    for (int et = 0; et < 4; ++et) {
      U4S8 bh, bl;
      bh.u = *(const uint4*)(bufp + 4096 + entry[et]);
      bl.u = *(const uint4*)(bufp + 8192 + entry[et]);
#pragma unroll
      for (int t = 0; t < 2; ++t) {
        acc[t][et] = __builtin_amdgcn_mfma_f32_16x16x32_bf16(ah[t], bh.s, acc[t][et], 0, 0, 0);
        acc[t][et] = __builtin_amdgcn_mfma_f32_16x16x32_bf16(ah[t], bl.s, acc[t][et], 0, 0, 0);
        acc[t][et] = __builtin_amdgcn_mfma_f32_16x16x32_bf16(al[t], bh.s, acc[t][et], 0, 0, 0);
      }
    }
  }

  // logits to LDS (all staging retired: vmcnt(0) at kc=127; single wave)
  float* lg = (float*)smraw;                    // [32][66]
#pragma unroll
  for (int t = 0; t < 2; ++t)
#pragma unroll
    for (int et = 0; et < 4; ++et)
#pragma unroll
      for (int r = 0; r < 4; ++r)
        lg[(t * 16 + kgrp * 4 + r) * 66 + et * 16 + trow] = acc[t][et][r];

  // epilogue: 32 tokens, lane = expert (round-5 proven body)
  float msum = 0.f;
  int cnt = 0;
#pragma unroll 1
  for (int it = 0; it < 32; ++it) {
    const float lf = lg[it * 66 + lane];

    float m = lf;
#pragma unroll
    for (int off = 32; off; off >>= 1) m = fmaxf(m, __shfl_xor(m, off));
    float p = expf(lf - m);
    float s = p;
#pragma unroll
    for (int off = 32; off; off >>= 1) s += __shfl_xor(s, off);
    msum += p / s;

    // top-9 by logit, descending, tie -> lowest index
    float cur = lf;
    float myv = 0.f;
    int myi = 0;
#pragma unroll
    for (int r = 0; r < 9; ++r) {
      float v = cur;
      int ix = lane;
#pragma unroll
      for (int off = 1; off < 64; off <<= 1) {
        float ov = __shfl_xor(v, off);
        int oi = __shfl_xor(ix, off);
        if (ov > v || (ov == v && oi < ix)) { v = ov; ix = oi; }
      }
      if (lane == r) { myv = v; myi = ix; }
      if (r < 8 && lane == ix) { cur = -INFINITY; ++cnt; }
    }

    const float m0 = __shfl(myv, 0);
    float e = expf(myv - m0);
    float sv = e;
    sv += __shfl_xor(sv, 1);
    sv += __shfl_xor(sv, 2);
    sv += __shfl_xor(sv, 4);
    const float wgtv = e / sv;
    const int tg = tok0 + it;
    if (lane < KTOP) {
      out[(size_t)tg * KTOP + lane] = (float)myi;
      out[(size_t)TTOT * KTOP + (size_t)tg * KTOP + lane] = wgtv;
    }

    const float nxt = __shfl(myv, (lane + 1) & 63);
    const bool gp = (lane < 8) && (myv - nxt < TAU);
    const unsigned long long anyg = __ballot(gp);
    const float v7 = __shfl(myv, 7);
    const unsigned long long msk = __ballot(lf >= v7 - DELTA);
    if (lane == 0) {
      const unsigned long long mv = anyg ? msk : 0ULL;
      wmask[tg] = (unsigned)mv;
      wmask[TTOT + tg] = (unsigned)(mv >> 32);
    }
  }
  waux[blockIdx.x * 128 + lane] = (float)cnt;
  waux[blockIdx.x * 128 + 64 + lane] = msum;
}

// Pass 2: fp64 recompute of candidate experts for flagged tokens only.
__global__ __launch_bounds__(256) void moe_pass2(
    const float* __restrict__ x, const float* __restrict__ w,
    const unsigned* __restrict__ wmask, float* __restrict__ out) {
  __shared__ unsigned slo[64], shi[64];
  __shared__ double red[4];
  __shared__ double cval[64];
  __shared__ int cidx[64];
  const int tid = threadIdx.x;
  const int lane = tid & 63, wid = tid >> 6;
  const int t0 = blockIdx.x * BT2;

  if (tid < 64) { slo[tid] = wmask[t0 + tid]; shi[tid] = wmask[TTOT + t0 + tid]; }
  __syncthreads();
  int myf = (tid < 64) ? ((slo[tid] | shi[tid]) != 0u) : 0;
  if (!__syncthreads_or(myf)) return;

#pragma unroll 1
  for (int tt = 0; tt < BT2; ++tt) {
    const unsigned lo = slo[tt], hi = shi[tt];
    if (!(lo | hi)) continue;
    const int t = t0 + tt;
    const unsigned long long m = ((unsigned long long)hi << 32) | lo;
    const float* xr = x + (size_t)t * H;
    int ncand = 0;
#pragma unroll 1
    for (int e = 0; e < 64; ++e) {
      if (!((m >> e) & 1ULL)) continue;
      const float* wr = w + (size_t)e * H;
      double d = 0.0;
#pragma unroll
      for (int q = 0; q < 16; ++q) {
        const int k = tid + 256 * q;
        d = fma((double)xr[k], (double)wr[k], d);
      }
#pragma unroll
      for (int off = 32; off; off >>= 1) d += __shfl_xor(d, off);
      if (lane == 0) red[wid] = d;
      __syncthreads();
      if (tid == 0) {
        cval[ncand] = red[0] + red[1] + red[2] + red[3];
        cidx[ncand] = e;
      }
      __syncthreads();
      ++ncand;
    }
    if (tid == 0) {
      double sel[8];
      int si[8];
      for (int r = 0; r < 8; ++r) {
        int best = 0;
        double bv = -1e300;
        for (int c2 = 0; c2 < ncand; ++c2)
          if (cval[c2] > bv) { bv = cval[c2]; best = c2; }
        sel[r] = cval[best]; si[r] = cidx[best];
        cval[best] = -1e301;
      }
      const double m0 = sel[0];
      float es[8], ssum = 0.f;
      for (int r = 0; r < 8; ++r) { es[r] = expf((float)(sel[r] - m0)); ssum += es[r]; }
      for (int r = 0; r < 8; ++r) {
        out[(size_t)t * KTOP + r] = (float)si[r];
        out[(size_t)TTOT * KTOP + (size_t)t * KTOP + r] = es[r] / ssum;
      }
    }
    __syncthreads();
  }
}

// aux = alpha * mean_b sum_e (count[b,e]/(S*K/E)) * (scoresum[b,e]/S)
__global__ __launch_bounds__(256) void moe_gate_aux(
    const float* __restrict__ waux, float* __restrict__ out) {
  const int tid = threadIdx.x;
  const int b = tid >> 6, e = tid & 63;
  float cnt = 0.f, ms = 0.f;
#pragma unroll 4
  for (int j = 0; j < 128; ++j) {
    const int blk = b * 128 + j;
    cnt += waux[blk * 128 + e];
    ms += waux[blk * 128 + 64 + e];
  }
  float term = (cnt * (1.f / 512.f)) * (ms * (1.f / 4096.f));
  __shared__ float red[4];
#pragma unroll
  for (int off = 32; off; off >>= 1) term += __shfl_xor(term, off);
  if ((tid & 63) == 0) red[tid >> 6] = term;
  __syncthreads();
  if (tid == 0) {
    float tot = red[0] + red[1] + red[2] + red[3];
    out[(size_t)TTOT * KTOP * 2] = tot * (0.001f / 4.f);
  }
}

extern "C" void kernel_launch(void* const* d_in, const int* in_sizes, int n_in,
                              void* d_out, int out_size, void* d_ws, size_t ws_size,
                              hipStream_t stream) {
  (void)in_sizes; (void)n_in; (void)out_size; (void)ws_size;
  const float* x = (const float*)d_in[0];
  const float* w = (const float*)d_in[1];
  float* out = (float*)d_out;
  uint4* wsimg = (uint4*)d_ws;                                   // 1 MB hi + 1 MB lo
  unsigned* wmask = (unsigned*)((char*)d_ws + (1 << 21));        // 128 KB
  float* waux = (float*)((char*)d_ws + (1 << 21) + 2 * TTOT * 4);// 256 KB
  (void)hipFuncSetAttribute((const void*)moe_pass1,
                            hipFuncAttributeMaxDynamicSharedMemorySize, 49152);
  w_prep<<<128, 256, 0, stream>>>(w, wsimg);
  moe_pass1<<<NB1, 64, 49152, stream>>>(x, wsimg, out, wmask, waux);
  moe_pass2<<<NB2, 256, 0, stream>>>(x, w, wmask, out);
  moe_gate_aux<<<1, 256, 0, stream>>>(waux, out);
}

// Round 11
// 246.733 us; speedup vs baseline: 1.4804x; 1.4804x over previous
//
#include <hip/hip_runtime.h>
#include <math.h>

#define H 4096
#define NE 64
#define KTOP 8
#define TTOT 16384
#define BT1 32
#define NB1 (TTOT / BT1)        // 512 pass1 blocks (2 per CU)
#define BT2 64
#define NB2 (TTOT / BT2)        // 256 pass2 blocks
#define TAU 1e-4f
#define DELTA 1e-3f

typedef __attribute__((ext_vector_type(8))) short bf16x8;
typedef __attribute__((ext_vector_type(4))) float f32x4;

union U4S8 { uint4 u; bf16x8 s; };

__device__ __forceinline__ unsigned bf16_rne(float f) {
  unsigned b = __float_as_uint(f);
  b += 0x7fffu + ((b >> 16) & 1u);
  return b >> 16;
}

// w fp32 -> hi/lo bf16, pre-swizzled per-32k-chunk images (proven r5-r10).
// Chunk c image: 256 uint4; index = e*4 + (s ^ ((e>>1)&3)), holding
// w[e][c*32 + s*8 .. +7]. hi = images 0..127, lo = +128*256 uint4.
__global__ __launch_bounds__(256) void w_prep(const float* __restrict__ w,
                                              uint4* __restrict__ wsimg) {
  const int sid = blockIdx.x * 256 + threadIdx.x;   // 0..32767
  const int e = sid >> 9;
  const int rem = sid & 511;
  const int c = rem >> 2;
  const int s = rem & 3;
  const float* src = w + (size_t)e * H + c * 32 + s * 8;
  float4 f0 = *(const float4*)src;
  float4 f1 = *(const float4*)(src + 4);
  float xf[8] = {f0.x, f0.y, f0.z, f0.w, f1.x, f1.y, f1.z, f1.w};
  unsigned hu[8], lu[8];
#pragma unroll
  for (int j = 0; j < 8; ++j) {
    hu[j] = bf16_rne(xf[j]);
    float hf = __uint_as_float(hu[j] << 16);
    lu[j] = bf16_rne(xf[j] - hf);
  }
  uint4 hp, lp;
  hp.x = hu[0] | (hu[1] << 16); hp.y = hu[2] | (hu[3] << 16);
  hp.z = hu[4] | (hu[5] << 16); hp.w = hu[6] | (hu[7] << 16);
  lp.x = lu[0] | (lu[1] << 16); lp.y = lu[2] | (lu[3] << 16);
  lp.z = lu[4] | (lu[5] << 16); lp.w = lu[6] | (lu[7] << 16);
  const int slotp = s ^ ((e >> 1) & 3);
  wsimg[(size_t)c * 256 + e * 4 + slotp] = hp;
  wsimg[(size_t)128 * 256 + (size_t)c * 256 + e * 4 + slotp] = lp;
}

// fp32x8 -> bf16 hi frag + residual lo frag (packed RNE cvt).
__device__ __forceinline__ void cvt_split(const float4 a, const float4 b,
                                          bf16x8* hi, bf16x8* lo) {
  float xf[8] = {a.x, a.y, a.z, a.w, b.x, b.y, b.z, b.w};
  unsigned ph[4], pl[4];
#pragma unroll
  for (int q = 0; q < 4; ++q)
    asm("v_cvt_pk_bf16_f32 %0, %1, %2" : "=v"(ph[q])
        : "v"(xf[2 * q]), "v"(xf[2 * q + 1]));
  float rs[8];
#pragma unroll
  for (int q = 0; q < 4; ++q) {
    rs[2 * q]     = xf[2 * q]     - __uint_as_float(ph[q] << 16);
    rs[2 * q + 1] = xf[2 * q + 1] - __uint_as_float(ph[q] & 0xffff0000u);
  }
#pragma unroll
  for (int q = 0; q < 4; ++q)
    asm("v_cvt_pk_bf16_f32 %0, %1, %2" : "=v"(pl[q])
        : "v"(rs[2 * q]), "v"(rs[2 * q + 1]));
  U4S8 h, l;
  h.u = (uint4){ph[0], ph[1], ph[2], ph[3]};
  l.u = (uint4){pl[0], pl[1], pl[2], pl[3]};
  *hi = h.s;
  *lo = l.s;
}

#define GLDS(GP, LP)                                                   \
  __builtin_amdgcn_global_load_lds(                                    \
      (const __attribute__((address_space(1))) void*)(GP),             \
      (__attribute__((address_space(3))) void*)(LP), 16, 0, 0)

// Pass 1: bf16-split MFMA router GEMM. 2-wave blocks, grid 512 -> 2
// independent blocks/CU. Wave = 16 tokens x 64 experts x full K; w ring
// shared by the 2 waves. Depth-3 ring of 24 KB K-steps (64 k each):
// [0,8K) x (2 tiles, swizzled), [8K,16K) w hi, [16K,24K) w lo.
// Per iter: vmcnt(12) (one step stays in flight), s_barrier, issue
// step c+2, compute step c.
__global__ __launch_bounds__(128, 1) void moe_pass1(
    const float* __restrict__ x, const uint4* __restrict__ wsimg,
    float* __restrict__ out, unsigned* __restrict__ wmask,
    float* __restrict__ waux) {
  extern __shared__ __align__(16) char smraw[];
  const int tid = threadIdx.x;         // 0..127
  const int lane = tid & 63;
  const int wid = tid >> 6;            // wave 0..1 = token tile
  const int tok0 = blockIdx.x * BT1;
  const int trow = lane & 15;
  const int kgrp = lane >> 4;

  // ---- staging sources ----
  // x: issue q in 0..3 covers LDS bytes [q*2048 + tid*16, +16).
  // tile=(addr>>12), row=(addr>>8)&15, inrow=addr&255; src pre-XOR-swizzled.
  const char* xsrc[4];
#pragma unroll
  for (int q = 0; q < 4; ++q) {
    const int a = q * 2048 + tid * 16;
    const int tile = a >> 12;
    const int row = (a >> 8) & 15;
    const int inrow = a & 255;
    const int sin = inrow ^ ((row & 7) << 4);
    xsrc[q] = (const char*)(x + (size_t)(tok0 + tile * 16 + row) * H) + sin;
  }
  // w: issue j in 0..7: hilo=j>>2, sub=(j>>1)&1, half=j&1 (linear copy).
  const uint4* wsrc[8];
  int wdst[8];
#pragma unroll
  for (int j = 0; j < 8; ++j) {
    const int hilo = j >> 2, sub = (j >> 1) & 1, half = j & 1;
    wsrc[j] = wsimg + (size_t)hilo * (128 * 256) + sub * 256 + half * 128 + tid;
    wdst[j] = 8192 + hilo * 8192 + sub * 4096 + half * 2048 + tid * 16;
  }

  f32x4 acc[4];
#pragma unroll
  for (int et = 0; et < 4; ++et) acc[et] = (f32x4){0.f, 0.f, 0.f, 0.f};

#define ISSUE_STEP(KC, BUF)                                              \
  do {                                                                   \
    char* bb = smraw + (size_t)(BUF) * 24576;                            \
    _Pragma("unroll") for (int q = 0; q < 4; ++q)                        \
      GLDS(xsrc[q] + (size_t)(KC) * 256, bb + q * 2048 + tid * 16);      \
    _Pragma("unroll") for (int j = 0; j < 8; ++j)                        \
      GLDS((const char*)(wsrc[j] + (size_t)(KC) * 512), bb + wdst[j]);   \
  } while (0)

  // prologue: steps 0,1 in flight (24 loads/thread)
  ISSUE_STEP(0, 0);
  ISSUE_STEP(1, 1);

  const int sx = (trow & 7) << 4;
  const int abase = wid * 4096 + trow * 256;
  int entry[4];
#pragma unroll
  for (int et = 0; et < 4; ++et) {
    const int e = et * 16 + trow;
    entry[et] = (e * 4 + (kgrp ^ ((e >> 1) & 3))) * 16;
  }

  // ---- main loop: 64 K-steps of 64 k ----
#pragma unroll 1
  for (int kc = 0; kc < 64; ++kc) {
    if (kc < 63) {
      asm volatile("s_waitcnt vmcnt(12)" ::: "memory");
    } else {
      asm volatile("s_waitcnt vmcnt(0)" ::: "memory");
    }
    __builtin_amdgcn_s_barrier();   // both waves' step-kc loads retired
    asm volatile("" ::: "memory");
    if (kc + 2 < 64) ISSUE_STEP(kc + 2, (kc + 2) % 3);

    const char* bufp = smraw + (size_t)(kc % 3) * 24576;
#pragma unroll
    for (int sub = 0; sub < 2; ++sub) {
      float4 v0 = *(const float4*)(bufp + abase + ((sub * 128 + kgrp * 32) ^ sx));
      float4 v1 = *(const float4*)(bufp + abase + ((sub * 128 + kgrp * 32 + 16) ^ sx));
      bf16x8 ah, al;
      cvt_split(v0, v1, &ah, &al);
#pragma unroll
      for (int et = 0; et < 4; ++et) {
        U4S8 bh, bl;
        bh.u = *(const uint4*)(bufp + 8192 + sub * 4096 + entry[et]);
        bl.u = *(const uint4*)(bufp + 16384 + sub * 4096 + entry[et]);
        acc[et] = __builtin_amdgcn_mfma_f32_16x16x32_bf16(ah, bh.s, acc[et], 0, 0, 0);
        acc[et] = __builtin_amdgcn_mfma_f32_16x16x32_bf16(ah, bl.s, acc[et], 0, 0, 0);
        acc[et] = __builtin_amdgcn_mfma_f32_16x16x32_bf16(al, bh.s, acc[et], 0, 0, 0);
      }
    }
  }

  // ---- logits to LDS (aliases ring; all loads+reads drained) ----
  __syncthreads();
  float* lg = (float*)smraw;                    // [32][66]
  float* msumA = (float*)(smraw + 8448);        // [2][64]
  float* cntA = (float*)(smraw + 8960);         // [2][64]
#pragma unroll
  for (int et = 0; et < 4; ++et)
#pragma unroll
    for (int r = 0; r < 4; ++r)
      lg[(wid * 16 + kgrp * 4 + r) * 66 + et * 16 + trow] = acc[et][r];
  __syncthreads();

  // ---- epilogue: each wave its 16 tokens, lane = expert (proven) ----
  float msum = 0.f;
  int cnt = 0;
#pragma unroll 1
  for (int it = 0; it < 16; ++it) {
    const int t = wid * 16 + it;
    const float lf = lg[t * 66 + lane];

    float m = lf;
#pragma unroll
    for (int off = 32; off; off >>= 1) m = fmaxf(m, __shfl_xor(m, off));
    float p = expf(lf - m);
    float s = p;
#pragma unroll
    for (int off = 32; off; off >>= 1) s += __shfl_xor(s, off);
    msum += p / s;

    // top-9 by logit, descending, tie -> lowest index
    float cur = lf;
    float myv = 0.f;
    int myi = 0;
#pragma unroll
    for (int r = 0; r < 9; ++r) {
      float v = cur;
      int ix = lane;
#pragma unroll
      for (int off = 1; off < 64; off <<= 1) {
        float ov = __shfl_xor(v, off);
        int oi = __shfl_xor(ix, off);
        if (ov > v || (ov == v && oi < ix)) { v = ov; ix = oi; }
      }
      if (lane == r) { myv = v; myi = ix; }
      if (r < 8 && lane == ix) { cur = -INFINITY; ++cnt; }
    }

    const float m0 = __shfl(myv, 0);
    float e = expf(myv - m0);
    float sv = e;
    sv += __shfl_xor(sv, 1);
    sv += __shfl_xor(sv, 2);
    sv += __shfl_xor(sv, 4);
    const float wgtv = e / sv;
    const int tg = tok0 + t;
    if (lane < KTOP) {
      out[(size_t)tg * KTOP + lane] = (float)myi;
      out[(size_t)TTOT * KTOP + (size_t)tg * KTOP + lane] = wgtv;
    }

    const float nxt = __shfl(myv, (lane + 1) & 63);
    const bool gp = (lane < 8) && (myv - nxt < TAU);
    const unsigned long long anyg = __ballot(gp);
    const float v7 = __shfl(myv, 7);
    const unsigned long long msk = __ballot(lf >= v7 - DELTA);
    if (lane == 0) {
      const unsigned long long mv = anyg ? msk : 0ULL;
      wmask[tg] = (unsigned)mv;
      wmask[TTOT + tg] = (unsigned)(mv >> 32);
    }
  }
  msumA[wid * 64 + lane] = msum;
  cntA[wid * 64 + lane] = (float)cnt;
  __syncthreads();
  if (tid < 64) {
    waux[blockIdx.x * 128 + tid] = cntA[tid] + cntA[64 + tid];
    waux[blockIdx.x * 128 + 64 + tid] = msumA[tid] + msumA[64 + tid];
  }
}

// Pass 2: fp64 recompute of candidate experts for flagged tokens only.
__global__ __launch_bounds__(256) void moe_pass2(
    const float* __restrict__ x, const float* __restrict__ w,
    const unsigned* __restrict__ wmask, float* __restrict__ out) {
  __shared__ unsigned slo[64], shi[64];
  __shared__ double red[4];
  __shared__ double cval[64];
  __shared__ int cidx[64];
  const int tid = threadIdx.x;
  const int lane = tid & 63, wid = tid >> 6;
  const int t0 = blockIdx.x * BT2;

  if (tid < 64) { slo[tid] = wmask[t0 + tid]; shi[tid] = wmask[TTOT + t0 + tid]; }
  __syncthreads();
  int myf = (tid < 64) ? ((slo[tid] | shi[tid]) != 0u) : 0;
  if (!__syncthreads_or(myf)) return;

#pragma unroll 1
  for (int tt = 0; tt < BT2; ++tt) {
    const unsigned lo = slo[tt], hi = shi[tt];
    if (!(lo | hi)) continue;
    const int t = t0 + tt;
    const unsigned long long m = ((unsigned long long)hi << 32) | lo;
    const float* xr = x + (size_t)t * H;
    int ncand = 0;
#pragma unroll 1
    for (int e = 0; e < 64; ++e) {
      if (!((m >> e) & 1ULL)) continue;
      const float* wr = w + (size_t)e * H;
      double d = 0.0;
#pragma unroll
      for (int q = 0; q < 16; ++q) {
        const int k = tid + 256 * q;
        d = fma((double)xr[k], (double)wr[k], d);
      }
#pragma unroll
      for (int off = 32; off; off >>= 1) d += __shfl_xor(d, off);
      if (lane == 0) red[wid] = d;
      __syncthreads();
      if (tid == 0) {
        cval[ncand] = red[0] + red[1] + red[2] + red[3];
        cidx[ncand] = e;
      }
      __syncthreads();
      ++ncand;
    }
    if (tid == 0) {
      double sel[8];
      int si[8];
      for (int r = 0; r < 8; ++r) {
        int best = 0;
        double bv = -1e300;
        for (int c2 = 0; c2 < ncand; ++c2)
          if (cval[c2] > bv) { bv = cval[c2]; best = c2; }
        sel[r] = cval[best]; si[r] = cidx[best];
        cval[best] = -1e301;
      }
      const double m0 = sel[0];
      float es[8], ssum = 0.f;
      for (int r = 0; r < 8; ++r) { es[r] = expf((float)(sel[r] - m0)); ssum += es[r]; }
      for (int r = 0; r < 8; ++r) {
        out[(size_t)t * KTOP + r] = (float)si[r];
        out[(size_t)TTOT * KTOP + (size_t)t * KTOP + r] = es[r] / ssum;
      }
    }
    __syncthreads();
  }
}

// aux = alpha * mean_b sum_e (count[b,e]/(S*K/E)) * (scoresum[b,e]/S)
__global__ __launch_bounds__(256) void moe_gate_aux(
    const float* __restrict__ waux, float* __restrict__ out) {
  const int tid = threadIdx.x;
  const int b = tid >> 6, e = tid & 63;
  float cnt = 0.f, ms = 0.f;
#pragma unroll 4
  for (int j = 0; j < 128; ++j) {
    const int blk = b * 128 + j;
    cnt += waux[blk * 128 + e];
    ms += waux[blk * 128 + 64 + e];
  }
  float term = (cnt * (1.f / 512.f)) * (ms * (1.f / 4096.f));
  __shared__ float red[4];
#pragma unroll
  for (int off = 32; off; off >>= 1) term += __shfl_xor(term, off);
  if ((tid & 63) == 0) red[tid >> 6] = term;
  __syncthreads();
  if (tid == 0) {
    float tot = red[0] + red[1] + red[2] + red[3];
    out[(size_t)TTOT * KTOP * 2] = tot * (0.001f / 4.f);
  }
}

extern "C" void kernel_launch(void* const* d_in, const int* in_sizes, int n_in,
                              void* d_out, int out_size, void* d_ws, size_t ws_size,
                              hipStream_t stream) {
  (void)in_sizes; (void)n_in; (void)out_size; (void)ws_size;
  const float* x = (const float*)d_in[0];
  const float* w = (const float*)d_in[1];
  float* out = (float*)d_out;
  uint4* wsimg = (uint4*)d_ws;                                   // 512K hi + 512K lo
  unsigned* wmask = (unsigned*)((char*)d_ws + (1 << 21));        // 128 KB
  float* waux = (float*)((char*)d_ws + (1 << 21) + 2 * TTOT * 4);// 256 KB
  (void)hipFuncSetAttribute((const void*)moe_pass1,
                            hipFuncAttributeMaxDynamicSharedMemorySize, 73728);
  w_prep<<<128, 256, 0, stream>>>(w, wsimg);
  moe_pass1<<<NB1, 128, 73728, stream>>>(x, wsimg, out, wmask, waux);
  moe_pass2<<<NB2, 256, 0, stream>>>(x, w, wmask, out);
  moe_gate_aux<<<1, 256, 0, stream>>>(waux, out);
}

// Round 12
// 217.090 us; speedup vs baseline: 1.6825x; 1.1365x over previous
//
#include <hip/hip_runtime.h>
#include <math.h>

#define H 4096
#define NE 64
#define KTOP 8
#define TTOT 16384
#define BT1 64
#define NB1 (TTOT / BT1)        // 256 pass1 blocks
#define NSTEP 128               // K-steps of 32
#define BT2 64
#define NB2 (TTOT / BT2)        // 256 pass2 blocks
#define TAU 1e-4f
#define DELTA 1e-3f

typedef __attribute__((ext_vector_type(8))) short bf16x8;
typedef __attribute__((ext_vector_type(4))) float f32x4;

union U4S8 { uint4 u; bf16x8 s; };

__device__ __forceinline__ unsigned bf16_rne(float f) {
  unsigned b = __float_as_uint(f);
  b += 0x7fffu + ((b >> 16) & 1u);
  return b >> 16;
}

// w fp32 -> hi/lo bf16, pre-swizzled per-32k-chunk images (proven r5-r11).
// Chunk c image: 256 uint4; index = e*4 + (s ^ ((e>>1)&3)), holding
// w[e][c*32 + s*8 .. +7]. hi = chunks 0..127 (512 KB), lo = +512 KB.
__global__ __launch_bounds__(256) void w_prep(const float* __restrict__ w,
                                              uint4* __restrict__ wsimg) {
  const int sid = blockIdx.x * 256 + threadIdx.x;   // 0..32767
  const int e = sid >> 9;
  const int rem = sid & 511;
  const int c = rem >> 2;
  const int s = rem & 3;
  const float* src = w + (size_t)e * H + c * 32 + s * 8;
  float4 f0 = *(const float4*)src;
  float4 f1 = *(const float4*)(src + 4);
  float xf[8] = {f0.x, f0.y, f0.z, f0.w, f1.x, f1.y, f1.z, f1.w};
  unsigned hu[8], lu[8];
#pragma unroll
  for (int j = 0; j < 8; ++j) {
    hu[j] = bf16_rne(xf[j]);
    float hf = __uint_as_float(hu[j] << 16);
    lu[j] = bf16_rne(xf[j] - hf);
  }
  uint4 hp, lp;
  hp.x = hu[0] | (hu[1] << 16); hp.y = hu[2] | (hu[3] << 16);
  hp.z = hu[4] | (hu[5] << 16); hp.w = hu[6] | (hu[7] << 16);
  lp.x = lu[0] | (lu[1] << 16); lp.y = lu[2] | (lu[3] << 16);
  lp.z = lu[4] | (lu[5] << 16); lp.w = lu[6] | (lu[7] << 16);
  const int slotp = s ^ ((e >> 1) & 3);
  wsimg[(size_t)c * 256 + e * 4 + slotp] = hp;
  wsimg[(size_t)128 * 256 + (size_t)c * 256 + e * 4 + slotp] = lp;
}

// fp32x8 -> bf16 hi frag + residual lo frag (packed RNE cvt).
__device__ __forceinline__ void cvt_split(const float4 a, const float4 b,
                                          bf16x8* hi, bf16x8* lo) {
  float xf[8] = {a.x, a.y, a.z, a.w, b.x, b.y, b.z, b.w};
  unsigned ph[4], pl[4];
#pragma unroll
  for (int q = 0; q < 4; ++q)
    asm("v_cvt_pk_bf16_f32 %0, %1, %2" : "=v"(ph[q])
        : "v"(xf[2 * q]), "v"(xf[2 * q + 1]));
  float rs[8];
#pragma unroll
  for (int q = 0; q < 4; ++q) {
    rs[2 * q]     = xf[2 * q]     - __uint_as_float(ph[q] << 16);
    rs[2 * q + 1] = xf[2 * q + 1] - __uint_as_float(ph[q] & 0xffff0000u);
  }
#pragma unroll
  for (int q = 0; q < 4; ++q)
    asm("v_cvt_pk_bf16_f32 %0, %1, %2" : "=v"(pl[q])
        : "v"(rs[2 * q]), "v"(rs[2 * q + 1]));
  U4S8 h, l;
  h.u = (uint4){ph[0], ph[1], ph[2], ph[3]};
  l.u = (uint4){pl[0], pl[1], pl[2], pl[3]};
  *hi = h.s;
  *lo = l.s;
}

#define GLDS(GP, LP)                                                   \
  __builtin_amdgcn_global_load_lds(                                    \
      (const __attribute__((address_space(1))) void*)(GP),             \
      (__attribute__((address_space(3))) void*)(LP), 16, 0, 0)

// Pass 1: bf16-split MFMA router GEMM. 16-wave block (1024 thr), grid 256.
// Wave = 16-token x 16-expert output tile; per K-step (32 k) each wave
// issues exactly ONE 1-KB global_load_lds (128 KB VMEM per wave total).
// Ring: 4 slots x 16 KB ([0,8K) x tile 64x32 fp32 row-swizzled,
// [8K,12K) w hi image, [12K,16K) w lo image).
// Per iter: vmcnt(2), lgkmcnt(0), s_barrier, issue c+3, compute c.
__global__ __launch_bounds__(1024, 1) void moe_pass1(
    const float* __restrict__ x, const uint4* __restrict__ wsimg,
    float* __restrict__ out, unsigned* __restrict__ wmask,
    float* __restrict__ waux) {
  extern __shared__ __align__(16) char smraw[];
  const int tid = threadIdx.x;         // 0..1023
  const int lane = tid & 63;
  const int wv = tid >> 6;             // wave 0..15
  const int tok0 = blockIdx.x * BT1;
  const int trow = lane & 15;
  const int kgrp = lane >> 4;

  // ---- this wave's 1-KB staging slice ----
  // waves 0..7: x rows wv*8..+7 (swizzled source); waves 8..15: w images.
  const char* gsrc;
  int gadv, ldso;
  if (wv < 8) {
    const int row = (wv << 3) + (lane >> 3);       // 0..63
    const int inrow = (lane & 7) * 16;
    const int sin = inrow ^ ((row & 7) << 4);      // pre-swizzled source
    gsrc = (const char*)(x + (size_t)(tok0 + row) * H) + sin;
    gadv = 128;                                    // 32 floats per step
    ldso = (wv << 10);
  } else {
    const int j = wv - 8;                          // 0..7: j<4 hi, j>=4 lo
    gsrc = (const char*)wsimg + ((j >= 4) ? (512 << 10) : 0) +
           ((j & 3) << 10) + lane * 16;
    gadv = 4096;                                   // one 4-KB image per step
    ldso = 8192 + (j << 10);
  }

#define ISSUE_STEP(KC)                                                  \
  GLDS(gsrc + (size_t)(KC) * gadv, smraw + (((KC) & 3) << 14) + ldso)

  // prologue: 3 steps in flight (3 GLDS per wave)
  ISSUE_STEP(0);
  ISSUE_STEP(1);
  ISSUE_STEP(2);

  // ---- compute-side constants: wave tile (tt = token tile, et = expert) ----
  const int tt = wv >> 2;              // 0..3
  const int et = wv & 3;               // 0..3
  const int arow = tt * 16 + trow;
  const int sx = (trow & 7) << 4;      // arow&7 == trow&7
  const int abase = arow * 128;
  const int e = et * 16 + trow;
  const int eidx = (e * 4 + (kgrp ^ ((e >> 1) & 3))) * 16;

  f32x4 acc = (f32x4){0.f, 0.f, 0.f, 0.f};

  // ---- main loop: 128 K-steps of 32 k ----
#pragma unroll 1
  for (int kc = 0; kc < NSTEP; ++kc) {
    if (kc <= NSTEP - 3) {
      asm volatile("s_waitcnt vmcnt(2)" ::: "memory");
    } else if (kc == NSTEP - 2) {
      asm volatile("s_waitcnt vmcnt(1)" ::: "memory");
    } else {
      asm volatile("s_waitcnt vmcnt(0)" ::: "memory");
    }
    asm volatile("s_waitcnt lgkmcnt(0)" ::: "memory");
    __builtin_amdgcn_s_barrier();
    asm volatile("" ::: "memory");
    if (kc + 3 < NSTEP) ISSUE_STEP(kc + 3);

    const char* slot = smraw + ((kc & 3) << 14);
    float4 v0 = *(const float4*)(slot + abase + ((kgrp * 32) ^ sx));
    float4 v1 = *(const float4*)(slot + abase + ((kgrp * 32 + 16) ^ sx));
    bf16x8 ah, al;
    cvt_split(v0, v1, &ah, &al);
    U4S8 bh, bl;
    bh.u = *(const uint4*)(slot + 8192 + eidx);
    bl.u = *(const uint4*)(slot + 12288 + eidx);
    acc = __builtin_amdgcn_mfma_f32_16x16x32_bf16(ah, bh.s, acc, 0, 0, 0);
    acc = __builtin_amdgcn_mfma_f32_16x16x32_bf16(ah, bl.s, acc, 0, 0, 0);
    acc = __builtin_amdgcn_mfma_f32_16x16x32_bf16(al, bh.s, acc, 0, 0, 0);
  }

  // ---- logits to LDS (aliases ring; vmcnt fully drained at last step) ----
  __syncthreads();
  float* lg = (float*)smraw;                       // [64][66]
  float* msumA = (float*)(smraw + 16896);          // [16][64]
  float* cntA = (float*)(smraw + 20992);           // [16][64]
#pragma unroll
  for (int r = 0; r < 4; ++r)
    lg[(tt * 16 + kgrp * 4 + r) * 66 + et * 16 + trow] = acc[r];
  __syncthreads();

  // ---- epilogue: 16 waves x 4 tokens, lane = expert (proven body) ----
  float msum = 0.f;
  int cnt = 0;
#pragma unroll 1
  for (int it = 0; it < 4; ++it) {
    const int t = wv * 4 + it;
    const float lf = lg[t * 66 + lane];

    float m = lf;
#pragma unroll
    for (int off = 32; off; off >>= 1) m = fmaxf(m, __shfl_xor(m, off));
    float p = expf(lf - m);
    float s = p;
#pragma unroll
    for (int off = 32; off; off >>= 1) s += __shfl_xor(s, off);
    msum += p / s;

    // top-9 by logit, descending, tie -> lowest index
    float cur = lf;
    float myv = 0.f;
    int myi = 0;
#pragma unroll
    for (int r = 0; r < 9; ++r) {
      float v = cur;
      int ix = lane;
#pragma unroll
      for (int off = 1; off < 64; off <<= 1) {
        float ov = __shfl_xor(v, off);
        int oi = __shfl_xor(ix, off);
        if (ov > v || (ov == v && oi < ix)) { v = ov; ix = oi; }
      }
      if (lane == r) { myv = v; myi = ix; }
      if (r < 8 && lane == ix) { cur = -INFINITY; ++cnt; }
    }

    const float m0 = __shfl(myv, 0);
    float ee = expf(myv - m0);
    float sv = ee;
    sv += __shfl_xor(sv, 1);
    sv += __shfl_xor(sv, 2);
    sv += __shfl_xor(sv, 4);
    const float wgtv = ee / sv;
    const int tg = tok0 + t;
    if (lane < KTOP) {
      out[(size_t)tg * KTOP + lane] = (float)myi;
      out[(size_t)TTOT * KTOP + (size_t)tg * KTOP + lane] = wgtv;
    }

    const float nxt = __shfl(myv, (lane + 1) & 63);
    const bool gp = (lane < 8) && (myv - nxt < TAU);
    const unsigned long long anyg = __ballot(gp);
    const float v7 = __shfl(myv, 7);
    const unsigned long long msk = __ballot(lf >= v7 - DELTA);
    if (lane == 0) {
      const unsigned long long mv = anyg ? msk : 0ULL;
      wmask[tg] = (unsigned)mv;
      wmask[TTOT + tg] = (unsigned)(mv >> 32);
    }
  }
  msumA[wv * 64 + lane] = msum;
  cntA[wv * 64 + lane] = (float)cnt;
  __syncthreads();
  if (tid < 64) {
    float c16 = 0.f, m16 = 0.f;
#pragma unroll
    for (int k = 0; k < 16; ++k) {
      c16 += cntA[k * 64 + tid];
      m16 += msumA[k * 64 + tid];
    }
    waux[blockIdx.x * 128 + tid] = c16;
    waux[blockIdx.x * 128 + 64 + tid] = m16;
  }
}

// Pass 2: fp64 recompute of candidate experts for flagged tokens only.
__global__ __launch_bounds__(256) void moe_pass2(
    const float* __restrict__ x, const float* __restrict__ w,
    const unsigned* __restrict__ wmask, float* __restrict__ out) {
  __shared__ unsigned slo[64], shi[64];
  __shared__ double red[4];
  __shared__ double cval[64];
  __shared__ int cidx[64];
  const int tid = threadIdx.x;
  const int lane = tid & 63, wid = tid >> 6;
  const int t0 = blockIdx.x * BT2;

  if (tid < 64) { slo[tid] = wmask[t0 + tid]; shi[tid] = wmask[TTOT + t0 + tid]; }
  __syncthreads();
  int myf = (tid < 64) ? ((slo[tid] | shi[tid]) != 0u) : 0;
  if (!__syncthreads_or(myf)) return;

#pragma unroll 1
  for (int tt = 0; tt < BT2; ++tt) {
    const unsigned lo = slo[tt], hi = shi[tt];
    if (!(lo | hi)) continue;
    const int t = t0 + tt;
    const unsigned long long m = ((unsigned long long)hi << 32) | lo;
    const float* xr = x + (size_t)t * H;
    int ncand = 0;
#pragma unroll 1
    for (int e = 0; e < 64; ++e) {
      if (!((m >> e) & 1ULL)) continue;
      const float* wr = w + (size_t)e * H;
      double d = 0.0;
#pragma unroll
      for (int q = 0; q < 16; ++q) {
        const int k = tid + 256 * q;
        d = fma((double)xr[k], (double)wr[k], d);
      }
#pragma unroll
      for (int off = 32; off; off >>= 1) d += __shfl_xor(d, off);
      if (lane == 0) red[wid] = d;
      __syncthreads();
      if (tid == 0) {
        cval[ncand] = red[0] + red[1] + red[2] + red[3];
        cidx[ncand] = e;
      }
      __syncthreads();
      ++ncand;
    }
    if (tid == 0) {
      double sel[8];
      int si[8];
      for (int r = 0; r < 8; ++r) {
        int best = 0;
        double bv = -1e300;
        for (int c2 = 0; c2 < ncand; ++c2)
          if (cval[c2] > bv) { bv = cval[c2]; best = c2; }
        sel[r] = cval[best]; si[r] = cidx[best];
        cval[best] = -1e301;
      }
      const double m0 = sel[0];
      float es[8], ssum = 0.f;
      for (int r = 0; r < 8; ++r) { es[r] = expf((float)(sel[r] - m0)); ssum += es[r]; }
      for (int r = 0; r < 8; ++r) {
        out[(size_t)t * KTOP + r] = (float)si[r];
        out[(size_t)TTOT * KTOP + (size_t)t * KTOP + r] = es[r] / ssum;
      }
    }
    __syncthreads();
  }
}

// aux = alpha * mean_b sum_e (count[b,e]/(S*K/E)) * (scoresum[b,e]/S)
__global__ __launch_bounds__(256) void moe_gate_aux(
    const float* __restrict__ waux, float* __restrict__ out) {
  const int tid = threadIdx.x;
  const int b = tid >> 6, e = tid & 63;
  float cnt = 0.f, ms = 0.f;
#pragma unroll 4
  for (int j = 0; j < 64; ++j) {
    const int blk = b * 64 + j;
    cnt += waux[blk * 128 + e];
    ms += waux[blk * 128 + 64 + e];
  }
  float term = (cnt * (1.f / 512.f)) * (ms * (1.f / 4096.f));
  __shared__ float red[4];
#pragma unroll
  for (int off = 32; off; off >>= 1) term += __shfl_xor(term, off);
  if ((tid & 63) == 0) red[tid >> 6] = term;
  __syncthreads();
  if (tid == 0) {
    float tot = red[0] + red[1] + red[2] + red[3];
    out[(size_t)TTOT * KTOP * 2] = tot * (0.001f / 4.f);
  }
}

extern "C" void kernel_launch(void* const* d_in, const int* in_sizes, int n_in,
                              void* d_out, int out_size, void* d_ws, size_t ws_size,
                              hipStream_t stream) {
  (void)in_sizes; (void)n_in; (void)out_size; (void)ws_size;
  const float* x = (const float*)d_in[0];
  const float* w = (const float*)d_in[1];
  float* out = (float*)d_out;
  uint4* wsimg = (uint4*)d_ws;                                   // 512K hi + 512K lo
  unsigned* wmask = (unsigned*)((char*)d_ws + (1 << 21));        // 128 KB
  float* waux = (float*)((char*)d_ws + (1 << 21) + 2 * TTOT * 4);// 128 KB
  (void)hipFuncSetAttribute((const void*)moe_pass1,
                            hipFuncAttributeMaxDynamicSharedMemorySize, 65536);
  w_prep<<<128, 256, 0, stream>>>(w, wsimg);
  moe_pass1<<<NB1, 1024, 65536, stream>>>(x, wsimg, out, wmask, waux);
  moe_pass2<<<NB2, 256, 0, stream>>>(x, w, wmask, out);
  moe_gate_aux<<<1, 256, 0, stream>>>(waux, out);
}